// Round 1
// baseline (671.628 us; speedup 1.0000x reference)
//
#include <hip/hip_runtime.h>

#define FA 75
#define FB 12
#define CC 100
#define NN 20000
#define EE 40000
#define GG 1000
#define BN_EPS 1e-5f

// workspace layout (float offsets)
#define OFF_W1P  0          // packed W1+b1: 7500 rows * 16 floats = 120000
#define OFF_AGG  120000     // [N, C] = 2,000,000
#define OFF_H    2120000    // [N, C] = 2,000,000
#define OFF_STAT 4120000    // mean[100] + rstd[100]
#define OFF_POOL 4120200    // [G, C] = 100,000
// total ~4.22M floats ~= 16.9 MB

// Pack W1 ([FB, FA*C] row-major) + b1 into rows of 16 floats:
// W1p[r*16 + b] = W1[b*7500 + r] (b<12), W1p[r*16+12] = b1[r], rest 0.
__global__ __launch_bounds__(256) void prep_kernel(
    const float* __restrict__ W1, const float* __restrict__ b1,
    float* __restrict__ W1p)
{
    int idx = blockIdx.x * 256 + threadIdx.x;
    if (idx >= 7500 * 16) return;
    int r = idx >> 4, k = idx & 15;
    float v = 0.f;
    if (k < 12) v = W1[k * 7500 + r];
    else if (k == 12) v = b1[r];
    W1p[idx] = v;
}

// Fused NNConv message + scatter:
// lane = edge, wave-uniform c-quarter q (25 channels per thread).
// msg[e,c] = sum_i x[src,i] * relu(b1[i*C+c] + sum_b ea[e,b]*W1[b,i*C+c])
__global__ __launch_bounds__(256) void msg_kernel(
    const float* __restrict__ x, const float* __restrict__ edge_attr,
    const float* __restrict__ W1p, const int* __restrict__ eidx,
    float* __restrict__ agg)
{
    const int lane = threadIdx.x & 63;
    const int q = __builtin_amdgcn_readfirstlane((int)(threadIdx.x >> 6)); // 0..3
    const int e = blockIdx.x * 64 + lane;                 // EE divisible by 64
    const int src = eidx[e];
    const int dst = eidx[EE + e];

    const float4* ea4 = (const float4*)(edge_attr + (size_t)e * FB);
    float4 a0 = ea4[0], a1 = ea4[1], a2 = ea4[2];

    float acc[25];
#pragma unroll
    for (int j = 0; j < 25; ++j) acc[j] = 0.f;

    const float* xrow = x + (size_t)src * FA;
    const int cbase = q * 25;

    for (int i = 0; i < FA; ++i) {
        float xi = xrow[i];
        const float* wbase = W1p + (size_t)(i * CC + cbase) * 16;
#pragma unroll
        for (int j = 0; j < 25; ++j) {
            const float4* w4 = (const float4*)(wbase + j * 16);
            float4 w0 = w4[0];
            float4 w1 = w4[1];
            float4 w2 = w4[2];
            float t = wbase[j * 16 + 12];   // b1
            t = fmaf(a0.x, w0.x, t);
            t = fmaf(a0.y, w0.y, t);
            t = fmaf(a0.z, w0.z, t);
            t = fmaf(a0.w, w0.w, t);
            t = fmaf(a1.x, w1.x, t);
            t = fmaf(a1.y, w1.y, t);
            t = fmaf(a1.z, w1.z, t);
            t = fmaf(a1.w, w1.w, t);
            t = fmaf(a2.x, w2.x, t);
            t = fmaf(a2.y, w2.y, t);
            t = fmaf(a2.z, w2.z, t);
            t = fmaf(a2.w, w2.w, t);
            t = fmaxf(t, 0.f);
            acc[j] = fmaf(xi, t, acc[j]);
        }
    }

    float* arow = agg + (size_t)dst * CC + cbase;
#pragma unroll
    for (int j = 0; j < 25; ++j) atomicAdd(arow + j, acc[j]);
}

// h = relu(x @ W_root + agg + bias), stored [N, C]
__global__ __launch_bounds__(256) void root_kernel(
    const float* __restrict__ x, const float* __restrict__ W_root,
    const float* __restrict__ bias, const float* __restrict__ agg,
    float* __restrict__ h)
{
    const int n = blockIdx.x * 256 + threadIdx.x;
    const bool ok = (n < NN);
    const float* xrow = x + (size_t)(ok ? n : 0) * FA;

    float acc[CC];
#pragma unroll
    for (int c = 0; c < CC; ++c) acc[c] = 0.f;

    for (int i = 0; i < FA; ++i) {
        float xi = ok ? xrow[i] : 0.f;
        const float* wrow = W_root + i * CC;   // uniform -> s_load
#pragma unroll
        for (int c = 0; c < CC; ++c) acc[c] = fmaf(xi, wrow[c], acc[c]);
    }

    if (ok) {
        const float* arow = agg + (size_t)n * CC;
        float* hrow = h + (size_t)n * CC;
#pragma unroll
        for (int c = 0; c < CC; ++c)
            hrow[c] = fmaxf(acc[c] + bias[c] + arow[c], 0.f);
    }
}

// per-channel batch mean / rstd (biased var), double accumulation
__global__ __launch_bounds__(256) void stats_kernel(
    const float* __restrict__ h, float* __restrict__ stats)
{
    const int c = blockIdx.x;   // 0..99
    double s = 0.0, s2 = 0.0;
    for (int n = threadIdx.x; n < NN; n += 256) {
        float v = h[(size_t)n * CC + c];
        s += v;
        s2 += (double)v * v;
    }
    __shared__ double sh[256];
    __shared__ double sh2[256];
    sh[threadIdx.x] = s;
    sh2[threadIdx.x] = s2;
    __syncthreads();
    for (int o = 128; o > 0; o >>= 1) {
        if (threadIdx.x < o) {
            sh[threadIdx.x] += sh[threadIdx.x + o];
            sh2[threadIdx.x] += sh2[threadIdx.x + o];
        }
        __syncthreads();
    }
    if (threadIdx.x == 0) {
        double mean = sh[0] / NN;
        double var = sh2[0] / NN - mean * mean;
        stats[c] = (float)mean;
        stats[CC + c] = 1.0f / sqrtf((float)var + BN_EPS);
    }
}

// batchnorm apply + global_add_pool via atomics
__global__ __launch_bounds__(256) void norm_pool_kernel(
    const float* __restrict__ h, const float* __restrict__ stats,
    const float* __restrict__ gamma, const float* __restrict__ beta,
    const int* __restrict__ batch, float* __restrict__ pooled)
{
    const int idx = blockIdx.x * 256 + threadIdx.x;
    if (idx >= NN * CC) return;
    const int n = idx / CC;
    const int c = idx - n * CC;
    float v = gamma[c] * (h[idx] - stats[c]) * stats[CC + c] + beta[c];
    atomicAdd(&pooled[(size_t)batch[n] * CC + c], v);
}

// out[g] = relu(pooled[g,:]) . W_out + b_out
__global__ __launch_bounds__(256) void out_kernel(
    const float* __restrict__ pooled, const float* __restrict__ W_out,
    const float* __restrict__ b_out, float* __restrict__ out)
{
    const int g = blockIdx.x * 256 + threadIdx.x;
    if (g >= GG) return;
    const float* prow = pooled + (size_t)g * CC;
    float s = b_out[0];
#pragma unroll 4
    for (int c = 0; c < CC; ++c)
        s = fmaf(fmaxf(prow[c], 0.f), W_out[c], s);
    out[g] = s;
}

extern "C" void kernel_launch(void* const* d_in, const int* in_sizes, int n_in,
                              void* d_out, int out_size, void* d_ws, size_t ws_size,
                              hipStream_t stream)
{
    const float* x         = (const float*)d_in[0];
    const float* edge_attr = (const float*)d_in[1];
    const float* W1        = (const float*)d_in[2];
    const float* b1        = (const float*)d_in[3];
    const float* W_root    = (const float*)d_in[4];
    const float* bias      = (const float*)d_in[5];
    const float* gamma     = (const float*)d_in[6];
    const float* beta      = (const float*)d_in[7];
    const float* W_out     = (const float*)d_in[8];
    const float* b_out     = (const float*)d_in[9];
    const int*   eidx      = (const int*)d_in[10];
    const int*   batch     = (const int*)d_in[11];

    float* ws     = (float*)d_ws;
    float* W1p    = ws + OFF_W1P;
    float* agg    = ws + OFF_AGG;
    float* h      = ws + OFF_H;
    float* stats  = ws + OFF_STAT;
    float* pooled = ws + OFF_POOL;
    float* out    = (float*)d_out;

    hipMemsetAsync(agg, 0, (size_t)NN * CC * sizeof(float), stream);
    hipMemsetAsync(pooled, 0, (size_t)GG * CC * sizeof(float), stream);

    prep_kernel<<<(7500 * 16 + 255) / 256, 256, 0, stream>>>(W1, b1, W1p);
    msg_kernel<<<EE / 64, 256, 0, stream>>>(x, edge_attr, W1p, eidx, agg);
    root_kernel<<<(NN + 255) / 256, 256, 0, stream>>>(x, W_root, bias, agg, h);
    stats_kernel<<<CC, 256, 0, stream>>>(h, stats);
    norm_pool_kernel<<<(NN * CC + 255) / 256, 256, 0, stream>>>(h, stats, gamma, beta, batch, pooled);
    out_kernel<<<(GG + 255) / 256, 256, 0, stream>>>(pooled, W_out, b_out, out);
}

// Round 2
// 383.575 us; speedup vs baseline: 1.7510x; 1.7510x over previous
//
#include <hip/hip_runtime.h>

#define FA 75
#define FB 12
#define CC 100
#define NN 20000
#define EE 40000
#define GG 1000
#define BN_EPS 1e-5f

// workspace layout (float offsets)
#define OFF_W1P   0          // packed W1+b1: 7500 rows * 16 floats = 120000
#define OFF_S     0          // S[C,G] = 100000 floats, reuses W1p region AFTER msg
#define OFF_AGGT  120000     // aggT [C, N] = 2,000,000
#define OFF_HT    2120000    // h_t  [C, N] = 2,000,000
#define OFF_STAT  4120000    // mean[100] + rstd[100]
#define OFF_START 4120200    // int start[G+1]
// total ~4.13M floats ~= 16.5 MB

// Pack W1 ([FB, FA*C] row-major) + b1 into rows of 16 floats:
// W1p[r*16 + b] = W1[b*7500 + r] (b<12), W1p[r*16+12] = b1[r], rest 0.
__global__ __launch_bounds__(256) void prep_kernel(
    const float* __restrict__ W1, const float* __restrict__ b1,
    float* __restrict__ W1p)
{
    int idx = blockIdx.x * 256 + threadIdx.x;
    if (idx >= 7500 * 16) return;
    int r = idx >> 4, k = idx & 15;
    float v = 0.f;
    if (k < 12) v = W1[k * 7500 + r];
    else if (k == 12) v = b1[r];
    W1p[idx] = v;
}

// molecule row ranges: start[g] = first node of molecule g (batch is sorted)
__global__ __launch_bounds__(256) void start_kernel(
    const int* __restrict__ batch, int* __restrict__ start)
{
    int n = blockIdx.x * 256 + threadIdx.x;
    if (n >= NN) return;
    int b = batch[n];
    int prev = (n == 0) ? -1 : batch[n - 1];
    for (int g = prev + 1; g <= b; ++g) start[g] = n;
    if (n == NN - 1)
        for (int g = b + 1; g <= GG; ++g) start[g] = NN;
}

// Fused NNConv message + scatter (channel-transposed agg).
// lane = edge; wave handles a uniform 5-channel group (20 groups per edge-block).
// grid = (E/64) * 5 blocks of 256 (4 waves = 4 channel groups).
__global__ __launch_bounds__(256) void msg_kernel(
    const float* __restrict__ x, const float* __restrict__ edge_attr,
    const float* __restrict__ W1p, const int* __restrict__ eidx,
    float* __restrict__ aggT)
{
    const int lane = threadIdx.x & 63;
    const int w = threadIdx.x >> 6;                    // 0..3
    const int eb = blockIdx.x / 5;
    const int cg = (blockIdx.x - eb * 5) * 4 + w;      // 0..19
    const int cbase = __builtin_amdgcn_readfirstlane(cg * 5);
    const int e = eb * 64 + lane;
    const int src = eidx[e];
    const int dst = eidx[EE + e];

    const float4* ea4 = (const float4*)(edge_attr + (size_t)e * FB);
    float4 a0 = ea4[0], a1 = ea4[1], a2 = ea4[2];

    float acc[5];
#pragma unroll
    for (int j = 0; j < 5; ++j) acc[j] = 0.f;

    const float* xrow = x + (size_t)src * FA;

    for (int i = 0; i < FA; ++i) {
        float xi = xrow[i];
        const float* wbase = W1p + (size_t)(i * CC + cbase) * 16;
#pragma unroll
        for (int j = 0; j < 5; ++j) {
            const float4* w4 = (const float4*)(wbase + j * 16);
            float4 w0 = w4[0];
            float4 w1 = w4[1];
            float4 w2 = w4[2];
            float t = wbase[j * 16 + 12];   // b1
            t = fmaf(a0.x, w0.x, t);
            t = fmaf(a0.y, w0.y, t);
            t = fmaf(a0.z, w0.z, t);
            t = fmaf(a0.w, w0.w, t);
            t = fmaf(a1.x, w1.x, t);
            t = fmaf(a1.y, w1.y, t);
            t = fmaf(a1.z, w1.z, t);
            t = fmaf(a1.w, w1.w, t);
            t = fmaf(a2.x, w2.x, t);
            t = fmaf(a2.y, w2.y, t);
            t = fmaf(a2.z, w2.z, t);
            t = fmaf(a2.w, w2.w, t);
            t = fmaxf(t, 0.f);
            acc[j] = fmaf(xi, t, acc[j]);
        }
    }

#pragma unroll
    for (int j = 0; j < 5; ++j)
        atomicAdd(&aggT[(size_t)(cbase + j) * NN + dst], acc[j]);
}

// h_t[c][n] = relu(x @ W_root + aggT + bias), channel-transposed.
// lane = node; wave handles a uniform 10-channel group.
// grid = ceil(N/64) * 5 blocks of 128 (2 waves = 2 channel groups).
__global__ __launch_bounds__(128) void root_kernel(
    const float* __restrict__ x, const float* __restrict__ W_root,
    const float* __restrict__ bias, const float* __restrict__ aggT,
    float* __restrict__ h_t)
{
    const int lane = threadIdx.x & 63;
    const int w = threadIdx.x >> 6;                    // 0..1
    const int nb = blockIdx.x / 5;
    const int cg = (blockIdx.x - nb * 5) * 2 + w;      // 0..9
    const int cbase = __builtin_amdgcn_readfirstlane(cg * 10);
    const int n = nb * 64 + lane;
    const bool ok = (n < NN);
    const int nc = ok ? n : NN - 1;
    const float* xrow = x + (size_t)nc * FA;

    float acc[10];
#pragma unroll
    for (int j = 0; j < 10; ++j) acc[j] = 0.f;

    for (int i = 0; i < FA; ++i) {
        float xi = xrow[i];
        const float* wrow = W_root + i * CC + cbase;   // uniform -> s_load
#pragma unroll
        for (int j = 0; j < 10; ++j) acc[j] = fmaf(xi, wrow[j], acc[j]);
    }

    if (ok) {
#pragma unroll
        for (int j = 0; j < 10; ++j) {
            size_t off = (size_t)(cbase + j) * NN + n;
            h_t[off] = fmaxf(acc[j] + bias[cbase + j] + aggT[off], 0.f);
        }
    }
}

// per-channel batch mean / rstd over h_t[c][:], coalesced float4 reads
__global__ __launch_bounds__(256) void stats_kernel(
    const float* __restrict__ h_t, float* __restrict__ stats)
{
    const int c = blockIdx.x;   // 0..99
    const float4* row = (const float4*)(h_t + (size_t)c * NN);
    double s = 0.0, s2 = 0.0;
    for (int k = threadIdx.x; k < NN / 4; k += 256) {
        float4 v = row[k];
        s += (double)v.x + (double)v.y + (double)v.z + (double)v.w;
        s2 += (double)v.x * v.x + (double)v.y * v.y
            + (double)v.z * v.z + (double)v.w * v.w;
    }
    __shared__ double sh[256];
    __shared__ double sh2[256];
    sh[threadIdx.x] = s;
    sh2[threadIdx.x] = s2;
    __syncthreads();
    for (int o = 128; o > 0; o >>= 1) {
        if (threadIdx.x < o) {
            sh[threadIdx.x] += sh[threadIdx.x + o];
            sh2[threadIdx.x] += sh2[threadIdx.x + o];
        }
        __syncthreads();
    }
    if (threadIdx.x == 0) {
        double mean = sh[0] / NN;
        double var = sh2[0] / NN - mean * mean;
        stats[c] = (float)mean;
        stats[CC + c] = 1.0f / sqrtf((float)var + BN_EPS);
    }
}

// raw per-(g,c) sums of h_t (BN folded in later algebraically): S[c][g]
__global__ __launch_bounds__(256) void pool_kernel(
    const float* __restrict__ h_t, const int* __restrict__ start,
    float* __restrict__ S)
{
    int t = blockIdx.x * 256 + threadIdx.x;
    if (t >= CC * GG) return;
    int c = t / GG;
    int g = t - c * GG;
    const float* col = h_t + (size_t)c * NN;
    int n1 = start[g + 1];
    float s = 0.f;
    for (int n = start[g]; n < n1; ++n) s += col[n];
    S[t] = s;
}

// out[g] = relu(A_c*S[c,g] + cnt_g*(beta_c - A_c*mean_c)) . W_out + b_out
__global__ __launch_bounds__(128) void out_kernel(
    const float* __restrict__ S, const float* __restrict__ stats,
    const float* __restrict__ gamma, const float* __restrict__ beta,
    const int* __restrict__ start, const float* __restrict__ W_out,
    const float* __restrict__ b_out, float* __restrict__ out)
{
    const int g = blockIdx.x;
    const int c = threadIdx.x;
    float v = 0.f;
    if (c < CC) {
        float mean = stats[c], rstd = stats[CC + c];
        float A = gamma[c] * rstd;
        float B = beta[c] - A * mean;
        float cnt = (float)(start[g + 1] - start[g]);
        float pooled = fmaf(A, S[(size_t)c * GG + g], cnt * B);
        v = fmaxf(pooled, 0.f) * W_out[c];
    }
    __shared__ float sh[128];
    sh[threadIdx.x] = v;
    __syncthreads();
    for (int o = 64; o > 0; o >>= 1) {
        if (threadIdx.x < o) sh[threadIdx.x] += sh[threadIdx.x + o];
        __syncthreads();
    }
    if (threadIdx.x == 0) out[g] = sh[0] + b_out[0];
}

extern "C" void kernel_launch(void* const* d_in, const int* in_sizes, int n_in,
                              void* d_out, int out_size, void* d_ws, size_t ws_size,
                              hipStream_t stream)
{
    const float* x         = (const float*)d_in[0];
    const float* edge_attr = (const float*)d_in[1];
    const float* W1        = (const float*)d_in[2];
    const float* b1        = (const float*)d_in[3];
    const float* W_root    = (const float*)d_in[4];
    const float* bias      = (const float*)d_in[5];
    const float* gamma     = (const float*)d_in[6];
    const float* beta      = (const float*)d_in[7];
    const float* W_out     = (const float*)d_in[8];
    const float* b_out     = (const float*)d_in[9];
    const int*   eidx      = (const int*)d_in[10];
    const int*   batch     = (const int*)d_in[11];

    float* ws    = (float*)d_ws;
    float* W1p   = ws + OFF_W1P;
    float* S     = ws + OFF_S;      // aliases W1p; used only after msg
    float* aggT  = ws + OFF_AGGT;
    float* h_t   = ws + OFF_HT;
    float* stats = ws + OFF_STAT;
    int*   start = (int*)(ws + OFF_START);
    float* out   = (float*)d_out;

    hipMemsetAsync(aggT, 0, (size_t)NN * CC * sizeof(float), stream);

    prep_kernel<<<(7500 * 16 + 255) / 256, 256, 0, stream>>>(W1, b1, W1p);
    start_kernel<<<(NN + 255) / 256, 256, 0, stream>>>(batch, start);
    msg_kernel<<<(EE / 64) * 5, 256, 0, stream>>>(x, edge_attr, W1p, eidx, aggT);
    root_kernel<<<((NN + 63) / 64) * 5, 128, 0, stream>>>(x, W_root, bias, aggT, h_t);
    stats_kernel<<<CC, 256, 0, stream>>>(h_t, stats);
    pool_kernel<<<(CC * GG + 255) / 256, 256, 0, stream>>>(h_t, start, S);
    out_kernel<<<GG, 128, 0, stream>>>(S, stats, gamma, beta, start, W_out, b_out, out);
}